// Round 6
// baseline (6805.788 us; speedup 1.0000x reference)
//
#include <hip/hip_runtime.h>
#include <hip/hip_bf16.h>

// Problem dims (fixed)
#define NA   128   // agents
#define NN_  16    // neighbors
#define SS   64    // timesteps
#define DD   128   // model dim
#define HH   4     // heads

#define XS   132   // padded LDS row stride for 64x128 fp32 tiles (132%32=4 -> max
                   // 2-way bank aliasing on row-strided access; 132*4B%16==0 for b128)

// ---------------------------------------------------------------------------
// Kernel 1: per (bn, h) block. Q/K/V proj, masked softmax, att_sum atomics,
// res_h = attn @ V_h -> res (fp32, staged in d_out's nb region).
// Kh padded to stride 33 (scores loop reads 64 t-rows: stride 32 = 64-way
// bank conflict, stride 33 = conflict-free). Sc padded to stride 65.
// ---------------------------------------------------------------------------
__global__ __launch_bounds__(256) void k_attn(
    const float* __restrict__ nbr,            // (2048,64,128) fp32
    const int* __restrict__ mask,             // (2048,64,64) int32 0/1
    const float* __restrict__ Wq,             // (128,128)
    const float* __restrict__ Wk,
    const float* __restrict__ Wv,
    float* __restrict__ att_sum,              // (128,4,64,64) fp32, pre-zeroed
    float* res_ws)                            // (2048,64,128) fp32 (aliases out_nb)
{
    const int bnh = blockIdx.x;
    const int h   = bnh & 3;
    const int bn  = bnh >> 2;
    const int b   = bn >> 4;
    const int tid = threadIdx.x;

    __shared__ float Esh[64 * 128];          // 32 KB; reused as Sc (64x65)
    __shared__ float Qh[64 * 32];            // 8 KB
    __shared__ float Kh[64 * 33];            // 8.25 KB (padded)
    __shared__ float Vh[64 * 32];            // 8 KB
    float* const Sc = Esh;                   // 64 x 65 (4160 <= 8192)

    const float* E = nbr + (size_t)bn * 64 * 128;
    for (int i = tid; i < 64 * 128; i += 256) Esh[i] = E[i];
    __syncthreads();

    const int col = h * 32;
    for (int i = tid; i < 64 * 32; i += 256) {
        const int s = i >> 5, k = i & 31;
        const float* er = Esh + s * 128;
        const float* wq = Wq + col + k;
        const float* wk = Wk + col + k;
        const float* wv = Wv + col + k;
        float aq = 0.f, ak = 0.f, av = 0.f;
        for (int d = 0; d < 128; ++d) {
            const float e = er[d];
            aq += e * wq[d * 128];
            ak += e * wk[d * 128];
            av += e * wv[d * 128];
        }
        Qh[s * 32 + k] = aq; Kh[s * 33 + k] = ak; Vh[s * 32 + k] = av;
    }
    __syncthreads();   // Esh dead -> Sc may overwrite

    const float iscale = 0.17677669529663687f; // 1/sqrt(32)
    const int* mrow = mask + (size_t)bn * 4096;
    for (int i = tid; i < 4096; i += 256) {
        const int s = i >> 6, t = i & 63;
        const float* qs = Qh + s * 32;
        const float* kt = Kh + t * 33;
        float a0 = 0.f, a1 = 0.f, a2 = 0.f, a3 = 0.f;   // 4 indep chains
#pragma unroll
        for (int k = 0; k < 32; k += 4) {
            a0 += qs[k]     * kt[k];
            a1 += qs[k + 1] * kt[k + 1];
            a2 += qs[k + 2] * kt[k + 2];
            a3 += qs[k + 3] * kt[k + 3];
        }
        const float acc = (a0 + a1) + (a2 + a3);
        Sc[s * 65 + t] = mrow[i] ? acc * iscale : -1e9f;
    }
    __syncthreads();

    if (tid < 64) {
        float* r = Sc + tid * 65;
        float m = r[0];
        for (int t = 1; t < 64; ++t) m = fmaxf(m, r[t]);
        float sum = 0.f;
        for (int t = 0; t < 64; ++t) { const float e = __expf(r[t] - m); r[t] = e; sum += e; }
        const float inv = 1.f / sum;
        for (int t = 0; t < 64; ++t) r[t] *= inv;
    }
    __syncthreads();

    float* as = att_sum + ((size_t)(b * 4 + h)) * 4096;
    for (int i = tid; i < 4096; i += 256)
        atomicAdd(as + i, Sc[(i >> 6) * 65 + (i & 63)]);

    for (int i = tid; i < 2048; i += 256) {
        const int s = i >> 5, d = i & 31;
        const float* sr = Sc + s * 65;
        const float* vc = Vh + d;
        float a0 = 0.f, a1 = 0.f;
#pragma unroll
        for (int t = 0; t < 64; t += 2) {
            a0 += sr[t]     * vc[t * 32];
            a1 += sr[t + 1] * vc[t * 32 + 32];
        }
        res_ws[((size_t)bn * 64 + s) * 128 + h * 32 + d] = a0 + a1;
    }
}

// ---------------------------------------------------------------------------
// FFN + LN epilogue, register-tiled: out = LN(relu(X@W1)@W2 + X)*g + b.
// shX: 64 x XS (post-LN input, also residual). shH: 64 x XS relu scratch.
// 4 f-tiles of 128. Phase A: thread = 4 rows x 8 cols, 32 acc, X via LDS
// broadcast, W1 tile streamed once. Phase B: thread = (s,q) 32 out-cols,
// 32 indep chains. All weight traffic per block: W1+W2 read ~once per wave.
// ---------------------------------------------------------------------------
__device__ __forceinline__ void ffn_ln_store(
    float* __restrict__ shX, float* __restrict__ shH,
    const float* __restrict__ W1, const float* __restrict__ W2,
    const float* __restrict__ g, const float* __restrict__ bb,
    float* outp)
{
    const int tid = threadIdx.x;
    const int s = tid >> 2, q = tid & 3;      // B-phase / LN mapping
    const int rg = (tid >> 4) * 4;            // A-phase rows rg..rg+3
    const int c8 = (tid & 15) * 8;            // A-phase col group (within tile)

    float O[32];                              // running output, residual-init
#pragma unroll
    for (int jj = 0; jj < 32; ++jj) O[jj] = shX[s * XS + q * 32 + jj];

    for (int tile = 0; tile < 4; ++tile) {
        float a[4][8];
#pragma unroll
        for (int r = 0; r < 4; ++r)
#pragma unroll
            for (int j = 0; j < 8; ++j) a[r][j] = 0.f;
        const float* w1p = W1 + tile * 128 + c8;
        for (int d = 0; d < 128; ++d) {
            float wv[8];
#pragma unroll
            for (int j = 0; j < 8; ++j) wv[j] = w1p[d * 512 + j];
            float xv[4];
#pragma unroll
            for (int r = 0; r < 4; ++r) xv[r] = shX[(rg + r) * XS + d];
#pragma unroll
            for (int r = 0; r < 4; ++r)
#pragma unroll
                for (int j = 0; j < 8; ++j) a[r][j] += xv[r] * wv[j];
        }
        __syncthreads();   // previous tile's B-phase readers done with shH
#pragma unroll
        for (int r = 0; r < 4; ++r)
#pragma unroll
            for (int j = 0; j < 8; ++j)
                shH[(rg + r) * XS + c8 + j] = fmaxf(a[r][j], 0.f);
        __syncthreads();
        const float* w2p = W2 + (size_t)(tile * 128) * 128 + q * 32;
        const float* hrow = shH + s * XS;
        for (int fl = 0; fl < 128; ++fl) {
            const float hv = hrow[fl];
            const float* wr = w2p + fl * 128;
#pragma unroll
            for (int jj = 0; jj < 32; ++jj) O[jj] += hv * wr[jj];
        }
    }

    // LN over 128 across the lane-quad
    float ps = 0.f;
#pragma unroll
    for (int jj = 0; jj < 32; ++jj) ps += O[jj];
    ps += __shfl_xor(ps, 1, 64); ps += __shfl_xor(ps, 2, 64);
    const float mean = ps * (1.f / 128.f);
    float pq = 0.f;
#pragma unroll
    for (int jj = 0; jj < 32; ++jj) { const float d = O[jj] - mean; pq += d * d; }
    pq += __shfl_xor(pq, 1, 64); pq += __shfl_xor(pq, 2, 64);
    const float rstd = rsqrtf(pq * (1.f / 128.f) + 1e-5f);
#pragma unroll
    for (int jj = 0; jj < 32; ++jj) {
        const int j = q * 32 + jj;
        outp[s * 128 + j] = (O[jj] - mean) * rstd * g[j] + bb[j];
    }
}

// ---------------------------------------------------------------------------
// Kernel 2: per bn. O = res @ W_fc + E; LN; FFN+LN -> nb (fp32).
// res_in / out_nb alias (element-exact): block reads its slice to LDS first.
// ---------------------------------------------------------------------------
__global__ __launch_bounds__(256) void k_mha_ffn(
    const float* __restrict__ nbr,
    const float* res_in,                      // aliases out_nb
    const float* __restrict__ Wfc,
    const float* __restrict__ g1, const float* __restrict__ b1,
    const float* __restrict__ W1, const float* __restrict__ W2,
    const float* __restrict__ g2, const float* __restrict__ b2,
    float* out_nb)                            // aliases res_in
{
    const int bn = blockIdx.x;
    const int tid = threadIdx.x;
    __shared__ float shX[64 * XS];   // 33.8 KB
    __shared__ float shH[64 * XS];   // 33.8 KB  (67.6 KB total -> 2 blocks/CU)

    const float* rp = res_in + (size_t)bn * 8192;
    for (int i = tid; i < 8192; i += 256) shX[(i >> 7) * XS + (i & 127)] = rp[i];
    __syncthreads();

    const int s = tid >> 2, q = tid & 3;
    const float* Erow = nbr + ((size_t)bn * 64 + s) * 128 + q * 32;
    float O[32];
#pragma unroll
    for (int jj = 0; jj < 32; ++jj) O[jj] = Erow[jj]; // residual
    const float* rr = shX + s * XS;
    for (int k = 0; k < 128; ++k) {
        const float rv = rr[k];
        const float* wr = Wfc + k * 128 + q * 32;
#pragma unroll
        for (int jj = 0; jj < 32; ++jj) O[jj] += rv * wr[jj];
    }
    float ps = 0.f;
#pragma unroll
    for (int jj = 0; jj < 32; ++jj) ps += O[jj];
    ps += __shfl_xor(ps, 1, 64); ps += __shfl_xor(ps, 2, 64);
    const float mean = ps * (1.f / 128.f);
    float pq = 0.f;
#pragma unroll
    for (int jj = 0; jj < 32; ++jj) { const float d = O[jj] - mean; pq += d * d; }
    pq += __shfl_xor(pq, 1, 64); pq += __shfl_xor(pq, 2, 64);
    const float rstd = rsqrtf(pq * (1.f / 128.f) + 1e-5f);
    __syncthreads(); // everyone done reading shX
#pragma unroll
    for (int jj = 0; jj < 32; ++jj) {
        const int j = q * 32 + jj;
        shX[s * XS + j] = (O[jj] - mean) * rstd * g1[j] + b1[j];
    }
    __syncthreads();

    ffn_ln_store(shX, shH, W1, W2, g2, b2, out_nb + (size_t)bn * 8192);
}

// ---------------------------------------------------------------------------
// Kernel 3a: per (b, h). self-softmax + att_factor/16 * att_sum; @ x_emb.
// xe padded to 129 (t-strided reads), A padded to 65.
// ---------------------------------------------------------------------------
__global__ __launch_bounds__(256) void k_self(
    const float* __restrict__ xemb,            // (128,64,128) fp32
    const float* __restrict__ att_sum,         // (128,4,64,64)
    const float* __restrict__ attf,            // scalar fp32
    float* __restrict__ res_si)                // (128,4,64,128) fp32
{
    const int bh = blockIdx.x;   // b*4 + h
    const int b = bh >> 2;
    const int tid = threadIdx.x;
    __shared__ float xe[64 * 129]; // 33 KB
    __shared__ float A[64 * 65];   // 16.6 KB

    const float* xp = xemb + (size_t)b * 8192;
    for (int i = tid; i < 8192; i += 256) xe[(i >> 7) * 129 + (i & 127)] = xp[i];
    __syncthreads();

    const float isc = 0.08838834764831845f; // 1/sqrt(128)
    for (int i = tid; i < 4096; i += 256) {
        const int s = i >> 6, t = i & 63;
        const float* xs = xe + s * 129;
        const float* xt = xe + t * 129;
        float a0 = 0.f, a1 = 0.f, a2 = 0.f, a3 = 0.f;
#pragma unroll
        for (int d = 0; d < 128; d += 4) {
            a0 += xs[d]     * xt[d];
            a1 += xs[d + 1] * xt[d + 1];
            a2 += xs[d + 2] * xt[d + 2];
            a3 += xs[d + 3] * xt[d + 3];
        }
        A[s * 65 + t] = ((a0 + a1) + (a2 + a3)) * isc;
    }
    __syncthreads();
    if (tid < 64) {
        float* r = A + tid * 65;
        float m = r[0];
        for (int t = 1; t < 64; ++t) m = fmaxf(m, r[t]);
        float sum = 0.f;
        for (int t = 0; t < 64; ++t) { const float e = __expf(r[t] - m); r[t] = e; sum += e; }
        const float inv = 1.f / sum;
        for (int t = 0; t < 64; ++t) r[t] *= inv;
    }
    __syncthreads();
    const float f = attf[0] * (1.f / 16.f);
    const float* as = att_sum + (size_t)bh * 4096;
    for (int i = tid; i < 4096; i += 256)
        A[(i >> 6) * 65 + (i & 63)] += f * as[i];
    __syncthreads();

    float* op = res_si + (size_t)bh * 8192;
    for (int i = tid; i < 8192; i += 256) {
        const int s = i >> 7, d = i & 127;
        const float* ar = A + s * 65;
        float a0 = 0.f, a1 = 0.f;
#pragma unroll
        for (int t = 0; t < 64; t += 2) {
            a0 += ar[t]     * xe[t * 129 + d];
            a1 += ar[t + 1] * xe[(t + 1) * 129 + d];
        }
        op[i] = a0 + a1;
    }
}

// ---------------------------------------------------------------------------
// Kernel 3b: per b. x1 = cat_h(res_si) @ W_SI; out x = FFN+LN (fp32).
// ---------------------------------------------------------------------------
__global__ __launch_bounds__(256) void k_si_ffn(
    const float* __restrict__ res_si,
    const float* __restrict__ WSI,             // (512,128)
    const float* __restrict__ W1, const float* __restrict__ W2,
    const float* __restrict__ g, const float* __restrict__ bb,
    float* __restrict__ out_x)
{
    const int b = blockIdx.x;
    const int tid = threadIdx.x;
    __shared__ float shX[64 * XS];
    __shared__ float shH[64 * XS];

    const int s = tid >> 2, q = tid & 3;
    float acc[32];
#pragma unroll
    for (int jj = 0; jj < 32; ++jj) acc[jj] = 0.f;
    const float* rs = res_si + (size_t)b * 4 * 8192;
    for (int h = 0; h < 4; ++h) {
        const float* row = rs + h * 8192 + s * 128;
        const float* wbase = WSI + h * 128 * 128 + q * 32;
        for (int d = 0; d < 128; ++d) {
            const float rv = row[d];
            const float* wr = wbase + d * 128;
#pragma unroll
            for (int jj = 0; jj < 32; ++jj) acc[jj] += rv * wr[jj];
        }
    }
#pragma unroll
    for (int jj = 0; jj < 32; ++jj) shX[s * XS + q * 32 + jj] = acc[jj];
    __syncthreads();

    ffn_ln_store(shX, shH, W1, W2, g, bb, out_x + (size_t)b * 8192);
}

// ---------------------------------------------------------------------------
extern "C" void kernel_launch(void* const* d_in, const int* in_sizes, int n_in,
                              void* d_out, int out_size, void* d_ws, size_t ws_size,
                              hipStream_t stream) {
    const float* x_emb = (const float*)d_in[0];
    const float* nbr   = (const float*)d_in[1];
    const int*   mask  = (const int*)d_in[2];  // int32 (proved by R3/R4 A/B)
    const float* attf  = (const float*)d_in[3];
    const float* Wq    = (const float*)d_in[4];
    const float* Wk    = (const float*)d_in[5];
    const float* Wv    = (const float*)d_in[6];
    const float* Wfc   = (const float*)d_in[7];
    const float* g_mha = (const float*)d_in[8];
    const float* b_mha = (const float*)d_in[9];
    const float* WSI   = (const float*)d_in[10];
    const float* W1s   = (const float*)d_in[11];
    const float* W2s   = (const float*)d_in[12];
    const float* gs    = (const float*)d_in[13];
    const float* bs    = (const float*)d_in[14];
    const float* W1i   = (const float*)d_in[15];
    const float* W2i   = (const float*)d_in[16];
    const float* gi    = (const float*)d_in[17];
    const float* bi    = (const float*)d_in[18];

    // workspace (~25 MB):
    //   [0, 8M)            att_sum fp32 (128*4*64*64)  -- zeroed each call
    //   [8M+256, +16.8M)   res_si fp32 (128*4*64*128)
    float* att_sum = (float*)d_ws;
    float* res_si = (float*)((char*)d_ws + (size_t)8 * 1024 * 1024 + 256);

    float* out_x  = (float*)d_out;                       // output 0: x
    float* out_nb = out_x + (size_t)NA * SS * DD;        // output 1: nb
    float* res_ws = out_nb;   // res staged in out_nb storage (element-exact)

    hipMemsetAsync(d_ws, 0, (size_t)NA * HH * SS * SS * sizeof(float), stream);

    k_attn<<<NA * NN_ * HH, 256, 0, stream>>>(nbr, mask, Wq, Wk, Wv,
                                              att_sum, res_ws);
    k_mha_ffn<<<NA * NN_, 256, 0, stream>>>(nbr, res_ws, Wfc, g_mha, b_mha,
                                            W1i, W2i, gi, bi, out_nb);
    k_self<<<NA * HH, 256, 0, stream>>>(x_emb, att_sum, attf, res_si);
    k_si_ffn<<<NA, 256, 0, stream>>>(res_si, WSI, W1s, W2s, gs, bs, out_x);
}

// Round 7
// 1498.058 us; speedup vs baseline: 4.5431x; 4.5431x over previous
//
#include <hip/hip_runtime.h>
#include <hip/hip_bf16.h>

// Problem dims (fixed)
#define NA   128   // agents
#define NN_  16    // neighbors
#define SS   64    // timesteps
#define DD   128   // model dim
#define HH   4     // heads

typedef __attribute__((ext_vector_type(8))) short bf16x8;   // 8 bf16 = 4 VGPRs
typedef __attribute__((ext_vector_type(4))) float floatx4;  // MFMA C/D

#define MFMA16(a, b, c) __builtin_amdgcn_mfma_f32_16x16x32_bf16((a), (b), (c), 0, 0, 0)

__device__ __forceinline__ short F2BS(float f) {
    __hip_bfloat16 h = __float2bfloat16(f);
    short s;
    __builtin_memcpy(&s, &h, 2);
    return s;
}

// ---------------------------------------------------------------------------
// Weight prep: bf16 + transpose so MFMA B-fragments (B[k][n], lane n=lane&15,
// k=quad*8+j) are 16B-contiguous reads: store W^T[n][k] row-major.
//   WfcT [128][128], W1iT/W1sT [512][128], W2iT/W2sT/WSIT [128][512]
// ---------------------------------------------------------------------------
__global__ __launch_bounds__(256) void k_prep(
    const float* __restrict__ Wfc, const float* __restrict__ W1i,
    const float* __restrict__ W2i, const float* __restrict__ WSI,
    const float* __restrict__ W1s, const float* __restrict__ W2s,
    short* __restrict__ WfcT, short* __restrict__ W1iT, short* __restrict__ W2iT,
    short* __restrict__ WSIT, short* __restrict__ W1sT, short* __restrict__ W2sT)
{
    const int i = blockIdx.x * 256 + threadIdx.x;   // [0, 65536)
    if (i < 128 * 128) {
        const int n = i >> 7, k = i & 127;
        WfcT[i] = F2BS(Wfc[k * 128 + n]);
    }
    {   // [512][128] from (128,512)
        const int n = i >> 7, k = i & 127;
        W1iT[i] = F2BS(W1i[k * 512 + n]);
        W1sT[i] = F2BS(W1s[k * 512 + n]);
    }
    {   // [128][512] from (512,128)
        const int n = i >> 9, f = i & 511;
        W2iT[i] = F2BS(W2i[f * 128 + n]);
        W2sT[i] = F2BS(W2s[f * 128 + n]);
        WSIT[i] = F2BS(WSI[f * 128 + n]);
    }
}

// ---------------------------------------------------------------------------
// Kernel 1 (unchanged R6): per (bn,h): QKV proj, masked softmax, att_sum
// atomics, attn@V -> res_ws (fp32, staged in d_out's nb region).
// ---------------------------------------------------------------------------
__global__ __launch_bounds__(256) void k_attn(
    const float* __restrict__ nbr,            // (2048,64,128) fp32
    const int* __restrict__ mask,             // (2048,64,64) int32 0/1
    const float* __restrict__ Wq,             // (128,128)
    const float* __restrict__ Wk,
    const float* __restrict__ Wv,
    float* __restrict__ att_sum,              // (128,4,64,64) fp32, pre-zeroed
    float* res_ws)                            // (2048,64,128) fp32
{
    const int bnh = blockIdx.x;
    const int h   = bnh & 3;
    const int bn  = bnh >> 2;
    const int b   = bn >> 4;
    const int tid = threadIdx.x;

    __shared__ float Esh[64 * 128];          // 32 KB; reused as Sc (64x65)
    __shared__ float Qh[64 * 32];
    __shared__ float Kh[64 * 33];            // padded
    __shared__ float Vh[64 * 32];
    float* const Sc = Esh;

    const float* E = nbr + (size_t)bn * 64 * 128;
    for (int i = tid; i < 64 * 128; i += 256) Esh[i] = E[i];
    __syncthreads();

    const int col = h * 32;
    for (int i = tid; i < 64 * 32; i += 256) {
        const int s = i >> 5, k = i & 31;
        const float* er = Esh + s * 128;
        const float* wq = Wq + col + k;
        const float* wk = Wk + col + k;
        const float* wv = Wv + col + k;
        float aq = 0.f, ak = 0.f, av = 0.f;
        for (int d = 0; d < 128; ++d) {
            const float e = er[d];
            aq += e * wq[d * 128];
            ak += e * wk[d * 128];
            av += e * wv[d * 128];
        }
        Qh[s * 32 + k] = aq; Kh[s * 33 + k] = ak; Vh[s * 32 + k] = av;
    }
    __syncthreads();   // Esh dead -> Sc may overwrite

    const float iscale = 0.17677669529663687f; // 1/sqrt(32)
    const int* mrow = mask + (size_t)bn * 4096;
    for (int i = tid; i < 4096; i += 256) {
        const int s = i >> 6, t = i & 63;
        const float* qs = Qh + s * 32;
        const float* kt = Kh + t * 33;
        float a0 = 0.f, a1 = 0.f, a2 = 0.f, a3 = 0.f;
#pragma unroll
        for (int k = 0; k < 32; k += 4) {
            a0 += qs[k]     * kt[k];
            a1 += qs[k + 1] * kt[k + 1];
            a2 += qs[k + 2] * kt[k + 2];
            a3 += qs[k + 3] * kt[k + 3];
        }
        const float acc = (a0 + a1) + (a2 + a3);
        Sc[s * 65 + t] = mrow[i] ? acc * iscale : -1e9f;
    }
    __syncthreads();

    if (tid < 64) {
        float* r = Sc + tid * 65;
        float m = r[0];
        for (int t = 1; t < 64; ++t) m = fmaxf(m, r[t]);
        float sum = 0.f;
        for (int t = 0; t < 64; ++t) { const float e = __expf(r[t] - m); r[t] = e; sum += e; }
        const float inv = 1.f / sum;
        for (int t = 0; t < 64; ++t) r[t] *= inv;
    }
    __syncthreads();

    float* as = att_sum + ((size_t)(b * 4 + h)) * 4096;
    for (int i = tid; i < 4096; i += 256)
        atomicAdd(as + i, Sc[(i >> 6) * 65 + (i & 63)]);

    for (int i = tid; i < 2048; i += 256) {
        const int s = i >> 5, d = i & 31;
        const float* sr = Sc + s * 65;
        const float* vc = Vh + d;
        float a0 = 0.f, a1 = 0.f;
#pragma unroll
        for (int t = 0; t < 64; t += 2) {
            a0 += sr[t]     * vc[t * 32];
            a1 += sr[t + 1] * vc[t * 32 + 32];
        }
        res_ws[((size_t)bn * 64 + s) * 128 + h * 32 + d] = a0 + a1;
    }
}

// ---------------------------------------------------------------------------
// MFMA FFN + LN: out = LN(relu(X@W1)@W2 + Xr)*g + b, M=64 (16 rows/wave).
// shA: [64][128] bf16 X. shH: [64][256] bf16 relu scratch (per f-half).
// Xr: residual, fp32 in C-layout regs. Wave-private rows -> NO barriers.
// ---------------------------------------------------------------------------
__device__ __forceinline__ void ffn_mfma(
    const short* shA, short* shH, float (&Xr)[8][4],
    const short* __restrict__ W1T,   // [512][128] bf16
    const short* __restrict__ W2T,   // [128][512] bf16
    const float* __restrict__ g, const float* __restrict__ bb,
    float* outp, int m0, int lane)
{
    const int quad = lane >> 4, l16 = lane & 15;

    bf16x8 ax[4];
#pragma unroll
    for (int kt = 0; kt < 4; ++kt)
        ax[kt] = *(const bf16x8*)&shA[(m0 + l16) * 128 + kt * 32 + quad * 8];

    floatx4 accO[8];
#pragma unroll
    for (int nt = 0; nt < 8; ++nt)
#pragma unroll
        for (int r = 0; r < 4; ++r) accO[nt][r] = Xr[nt][r];

#pragma unroll
    for (int hf = 0; hf < 2; ++hf) {
        // H-half = relu(X @ W1[:, hf*256 : hf*256+256])
#pragma unroll
        for (int nt = 0; nt < 16; ++nt) {
            floatx4 acc = {0.f, 0.f, 0.f, 0.f};
            const int n0 = hf * 256 + nt * 16;
#pragma unroll
            for (int kt = 0; kt < 4; ++kt) {
                bf16x8 bf = *(const bf16x8*)&W1T[(size_t)(n0 + l16) * 128 + kt * 32 + quad * 8];
                acc = MFMA16(ax[kt], bf, acc);
            }
#pragma unroll
            for (int r = 0; r < 4; ++r)
                shH[(m0 + quad * 4 + r) * 256 + nt * 16 + l16] = F2BS(fmaxf(acc[r], 0.f));
        }
        // O += H-half @ W2[hf*256 : , :]   (in-wave LDS ordering: safe)
        bf16x8 ah[8];
#pragma unroll
        for (int kt = 0; kt < 8; ++kt)
            ah[kt] = *(const bf16x8*)&shH[(m0 + l16) * 256 + kt * 32 + quad * 8];
#pragma unroll
        for (int nt = 0; nt < 8; ++nt)
#pragma unroll
            for (int kt = 0; kt < 8; ++kt) {
                bf16x8 bf = *(const bf16x8*)&W2T[(size_t)(nt * 16 + l16) * 512 + hf * 256 + kt * 32 + quad * 8];
                accO[nt] = MFMA16(ah[kt], bf, accO[nt]);
            }
    }

    // LayerNorm: row = m0 + quad*4 + r; 128 cols = 8 frags x 16 quad-lanes
    float mean[4], rstd[4];
#pragma unroll
    for (int r = 0; r < 4; ++r) {
        float p = 0.f;
#pragma unroll
        for (int nt = 0; nt < 8; ++nt) p += accO[nt][r];
        p += __shfl_xor(p, 1, 64); p += __shfl_xor(p, 2, 64);
        p += __shfl_xor(p, 4, 64); p += __shfl_xor(p, 8, 64);
        mean[r] = p * (1.f / 128.f);
        float q = 0.f;
#pragma unroll
        for (int nt = 0; nt < 8; ++nt) { const float d = accO[nt][r] - mean[r]; q += d * d; }
        q += __shfl_xor(q, 1, 64); q += __shfl_xor(q, 2, 64);
        q += __shfl_xor(q, 4, 64); q += __shfl_xor(q, 8, 64);
        rstd[r] = rsqrtf(q * (1.f / 128.f) + 1e-5f);
    }
#pragma unroll
    for (int nt = 0; nt < 8; ++nt) {
        const int colc = nt * 16 + l16;
        const float gc = g[colc], bc = bb[colc];
#pragma unroll
        for (int r = 0; r < 4; ++r) {
            const int row = m0 + quad * 4 + r;
            outp[row * 128 + colc] = (accO[nt][r] - mean[r]) * rstd[r] * gc + bc;
        }
    }
}

// ---------------------------------------------------------------------------
// Kernel 2 (MFMA): per bn. O = res@Wfc + E; LN -> X; FFN+LN -> nb.
// res_in aliases out_nb (block reads own slice before writing). Barrier-free:
// every wave touches only its own 16 rows of shA/shH.
// ---------------------------------------------------------------------------
__global__ __launch_bounds__(256) void k_mha_ffn(
    const float* __restrict__ nbr,
    const float* res_in,                      // aliases out_nb
    const short* __restrict__ WfcT,           // [128][128] bf16
    const float* __restrict__ g1, const float* __restrict__ b1,
    const short* __restrict__ W1T, const short* __restrict__ W2T,
    const float* __restrict__ g2, const float* __restrict__ b2,
    float* out_nb)
{
    const int bn = blockIdx.x, tid = threadIdx.x;
    const int w = tid >> 6, lane = tid & 63, quad = lane >> 4, l16 = lane & 15;
    const int m0 = w * 16;
    __shared__ short shA[64 * 128];  // 16 KB
    __shared__ short shH[64 * 256];  // 32 KB

    // stage own 16 rows of res as bf16
    const float* rp = res_in + (size_t)bn * 8192;
    for (int i = lane; i < 2048; i += 64) {
        const int row = m0 + (i >> 7), colc = i & 127;
        shA[row * 128 + colc] = F2BS(rp[row * 128 + colc]);
    }

    bf16x8 ax[4];
#pragma unroll
    for (int kt = 0; kt < 4; ++kt)
        ax[kt] = *(const bf16x8*)&shA[(m0 + l16) * 128 + kt * 32 + quad * 8];

    // O = res @ Wfc + E
    floatx4 acc1[8];
    const float* Eb = nbr + (size_t)bn * 8192;
#pragma unroll
    for (int nt = 0; nt < 8; ++nt)
#pragma unroll
        for (int r = 0; r < 4; ++r)
            acc1[nt][r] = Eb[(m0 + quad * 4 + r) * 128 + nt * 16 + l16];
#pragma unroll
    for (int nt = 0; nt < 8; ++nt)
#pragma unroll
        for (int kt = 0; kt < 4; ++kt) {
            bf16x8 bf = *(const bf16x8*)&WfcT[(size_t)(nt * 16 + l16) * 128 + kt * 32 + quad * 8];
            acc1[nt] = MFMA16(ax[kt], bf, acc1[nt]);
        }

    // LN -> X (regs, fp32) + bf16 copy into shA (own rows)
    float mean[4], rstd[4];
#pragma unroll
    for (int r = 0; r < 4; ++r) {
        float p = 0.f;
#pragma unroll
        for (int nt = 0; nt < 8; ++nt) p += acc1[nt][r];
        p += __shfl_xor(p, 1, 64); p += __shfl_xor(p, 2, 64);
        p += __shfl_xor(p, 4, 64); p += __shfl_xor(p, 8, 64);
        mean[r] = p * (1.f / 128.f);
        float q = 0.f;
#pragma unroll
        for (int nt = 0; nt < 8; ++nt) { const float d = acc1[nt][r] - mean[r]; q += d * d; }
        q += __shfl_xor(q, 1, 64); q += __shfl_xor(q, 2, 64);
        q += __shfl_xor(q, 4, 64); q += __shfl_xor(q, 8, 64);
        rstd[r] = rsqrtf(q * (1.f / 128.f) + 1e-5f);
    }
    float Xr[8][4];
#pragma unroll
    for (int nt = 0; nt < 8; ++nt) {
        const int colc = nt * 16 + l16;
        const float gc = g1[colc], bc = b1[colc];
#pragma unroll
        for (int r = 0; r < 4; ++r) {
            Xr[nt][r] = (acc1[nt][r] - mean[r]) * rstd[r] * gc + bc;
            shA[(m0 + quad * 4 + r) * 128 + colc] = F2BS(Xr[nt][r]);
        }
    }

    ffn_mfma(shA, shH, Xr, W1T, W2T, g2, b2, out_nb + (size_t)bn * 8192, m0, lane);
}

// ---------------------------------------------------------------------------
// Kernel 3a (unchanged R6): self-softmax + att_factor/16*att_sum; @ x_emb.
// ---------------------------------------------------------------------------
__global__ __launch_bounds__(256) void k_self(
    const float* __restrict__ xemb,            // (128,64,128) fp32
    const float* __restrict__ att_sum,         // (128,4,64,64)
    const float* __restrict__ attf,            // scalar fp32
    float* __restrict__ res_si)                // (128,4,64,128) fp32
{
    const int bh = blockIdx.x;   // b*4 + h
    const int b = bh >> 2;
    const int tid = threadIdx.x;
    __shared__ float xe[64 * 129];
    __shared__ float A[64 * 65];

    const float* xp = xemb + (size_t)b * 8192;
    for (int i = tid; i < 8192; i += 256) xe[(i >> 7) * 129 + (i & 127)] = xp[i];
    __syncthreads();

    const float isc = 0.08838834764831845f; // 1/sqrt(128)
    for (int i = tid; i < 4096; i += 256) {
        const int s = i >> 6, t = i & 63;
        const float* xs = xe + s * 129;
        const float* xt = xe + t * 129;
        float a0 = 0.f, a1 = 0.f, a2 = 0.f, a3 = 0.f;
#pragma unroll
        for (int d = 0; d < 128; d += 4) {
            a0 += xs[d]     * xt[d];
            a1 += xs[d + 1] * xt[d + 1];
            a2 += xs[d + 2] * xt[d + 2];
            a3 += xs[d + 3] * xt[d + 3];
        }
        A[s * 65 + t] = ((a0 + a1) + (a2 + a3)) * isc;
    }
    __syncthreads();
    if (tid < 64) {
        float* r = A + tid * 65;
        float m = r[0];
        for (int t = 1; t < 64; ++t) m = fmaxf(m, r[t]);
        float sum = 0.f;
        for (int t = 0; t < 64; ++t) { const float e = __expf(r[t] - m); r[t] = e; sum += e; }
        const float inv = 1.f / sum;
        for (int t = 0; t < 64; ++t) r[t] *= inv;
    }
    __syncthreads();
    const float f = attf[0] * (1.f / 16.f);
    const float* as = att_sum + (size_t)bh * 4096;
    for (int i = tid; i < 4096; i += 256)
        A[(i >> 6) * 65 + (i & 63)] += f * as[i];
    __syncthreads();

    float* op = res_si + (size_t)bh * 8192;
    for (int i = tid; i < 8192; i += 256) {
        const int s = i >> 7, d = i & 127;
        const float* ar = A + s * 65;
        float a0 = 0.f, a1 = 0.f;
#pragma unroll
        for (int t = 0; t < 64; t += 2) {
            a0 += ar[t]     * xe[t * 129 + d];
            a1 += ar[t + 1] * xe[(t + 1) * 129 + d];
        }
        op[i] = a0 + a1;
    }
}

// ---------------------------------------------------------------------------
// Kernel 3b (MFMA): per b. X1 = cat_h(res_si)@W_SI (K=512); FFN+LN -> x.
// shC [64][512] bf16 for step A; after one barrier the same LDS is re-split
// into shA[64][128] + shH[64][256] (wave-private rows).
// ---------------------------------------------------------------------------
__global__ __launch_bounds__(256) void k_si_ffn(
    const float* __restrict__ res_si,
    const short* __restrict__ WSIT,            // [128][512] bf16
    const short* __restrict__ W1T, const short* __restrict__ W2T,
    const float* __restrict__ g, const float* __restrict__ bb,
    float* __restrict__ out_x)
{
    const int b = blockIdx.x, tid = threadIdx.x;
    const int w = tid >> 6, lane = tid & 63, quad = lane >> 4, l16 = lane & 15;
    const int m0 = w * 16;
    __shared__ short shC[64 * 512];            // 64 KB
    short* shA = shC;                          // [64][128] after barrier
    short* shH = shC + 64 * 128;               // [64][256] after barrier

    // stage own 16 rows of cat_h(res_si) as bf16: row s, k = h*128+d
    const float* rs = res_si + (size_t)b * 4 * 8192;
    for (int i = lane; i < 8192; i += 64) {
        const int row = m0 + (i >> 9), k = i & 511;
        const int h = k >> 7, d = k & 127;
        shC[row * 512 + k] = F2BS(rs[((size_t)h * 64 + row) * 128 + d]);
    }

    // X1 = cat @ W_SI  (M=64,K=512,N=128), no residual/LN
    floatx4 acc1[8];
#pragma unroll
    for (int nt = 0; nt < 8; ++nt) acc1[nt] = (floatx4){0.f, 0.f, 0.f, 0.f};
    for (int kt = 0; kt < 16; ++kt) {
        bf16x8 a = *(const bf16x8*)&shC[(m0 + l16) * 512 + kt * 32 + quad * 8];
#pragma unroll
        for (int nt = 0; nt < 8; ++nt) {
            bf16x8 bf = *(const bf16x8*)&WSIT[(size_t)(nt * 16 + l16) * 512 + kt * 32 + quad * 8];
            acc1[nt] = MFMA16(a, bf, acc1[nt]);
        }
    }
    float Xr[8][4];
#pragma unroll
    for (int nt = 0; nt < 8; ++nt)
#pragma unroll
        for (int r = 0; r < 4; ++r) Xr[nt][r] = acc1[nt][r];

    __syncthreads();   // all step-A reads of shC done before overlay writes

#pragma unroll
    for (int nt = 0; nt < 8; ++nt)
#pragma unroll
        for (int r = 0; r < 4; ++r)
            shA[(m0 + quad * 4 + r) * 128 + nt * 16 + l16] = F2BS(Xr[nt][r]);

    ffn_mfma(shA, shH, Xr, W1T, W2T, g, bb, out_x + (size_t)b * 8192, m0, lane);
}

// ---------------------------------------------------------------------------
extern "C" void kernel_launch(void* const* d_in, const int* in_sizes, int n_in,
                              void* d_out, int out_size, void* d_ws, size_t ws_size,
                              hipStream_t stream) {
    const float* x_emb = (const float*)d_in[0];
    const float* nbr   = (const float*)d_in[1];
    const int*   mask  = (const int*)d_in[2];
    const float* attf  = (const float*)d_in[3];
    const float* Wq    = (const float*)d_in[4];
    const float* Wk    = (const float*)d_in[5];
    const float* Wv    = (const float*)d_in[6];
    const float* Wfc   = (const float*)d_in[7];
    const float* g_mha = (const float*)d_in[8];
    const float* b_mha = (const float*)d_in[9];
    const float* WSI   = (const float*)d_in[10];
    const float* W1s   = (const float*)d_in[11];
    const float* W2s   = (const float*)d_in[12];
    const float* gs    = (const float*)d_in[13];
    const float* bs    = (const float*)d_in[14];
    const float* W1i   = (const float*)d_in[15];
    const float* W2i   = (const float*)d_in[16];
    const float* gi    = (const float*)d_in[17];
    const float* bi    = (const float*)d_in[18];

    // workspace (~27 MB):
    //   [0, 8M)            att_sum fp32 (zeroed each call)
    //   [8M+256, +16.78M)  res_si fp32 (128*4*64*128)
    //   [26M, +656K)       bf16 transposed weights
    float* att_sum = (float*)d_ws;
    float* res_si = (float*)((char*)d_ws + (size_t)8 * 1024 * 1024 + 256);
    short* wb   = (short*)((char*)d_ws + (size_t)26 * 1024 * 1024);
    short* WfcT = wb;                  // 16384
    short* W1iT = WfcT + 16384;        // 65536
    short* W2iT = W1iT + 65536;
    short* WSIT = W2iT + 65536;
    short* W1sT = WSIT + 65536;
    short* W2sT = W1sT + 65536;

    float* out_x  = (float*)d_out;                       // output 0: x
    float* out_nb = out_x + (size_t)NA * SS * DD;        // output 1: nb
    float* res_ws = out_nb;   // res staged in out_nb storage (element-exact)

    hipMemsetAsync(d_ws, 0, (size_t)NA * HH * SS * SS * sizeof(float), stream);

    k_prep<<<256, 256, 0, stream>>>(Wfc, W1i, W2i, WSI, W1s, W2s,
                                    WfcT, W1iT, W2iT, WSIT, W1sT, W2sT);
    k_attn<<<NA * NN_ * HH, 256, 0, stream>>>(nbr, mask, Wq, Wk, Wv,
                                              att_sum, res_ws);
    k_mha_ffn<<<NA * NN_, 256, 0, stream>>>(nbr, res_ws, WfcT, g_mha, b_mha,
                                            W1iT, W2iT, gi, bi, out_nb);
    k_self<<<NA * HH, 256, 0, stream>>>(x_emb, att_sum, attf, res_si);
    k_si_ffn<<<NA, 256, 0, stream>>>(res_si, WSIT, W1sT, W2sT, gs, bs, out_x);
}